// Round 8
// baseline (96.229 us; speedup 1.0000x reference)
//
#include <hip/hip_runtime.h>
#include <math.h>

#define THREADS 256

constexpr int S   = 8;
constexpr int NPT = 64;
constexpr int SD  = 36;
constexpr float EPS = 1e-5f;

typedef float v4f __attribute__((ext_vector_type(4)));
typedef __attribute__((ext_vector_type(8))) short bf8;   // 8 bf16 (4 VGPR)
typedef __attribute__((ext_vector_type(4))) float f4;    // MFMA accumulator

__device__ __forceinline__ float lrelu(float x) { return x > 0.f ? x : 0.01f * x; }

// float -> bf16 round-to-nearest-even
__device__ __forceinline__ unsigned short f2bf(float x) {
  union { float f; unsigned u; } v; v.f = x;
  unsigned r = v.u + 0x7FFFu + ((v.u >> 16) & 1u);
  return (unsigned short)(r >> 16);
}

// ==================== fragment packing (one-time prep) ====================
// B-fragment: frag f = kt*NT + nt; lane l holds n = nt*16 + (l&15),
// k = kt*32 + (l>>4)*8 + j, j=0..7. TS>0: 2-tap conv weight [2][CIN][N] with
// tap stride TS (zero-pad c >= CIN). TS==0: flat [K][N].
__device__ __forceinline__ void pack_frag(const float* __restrict__ src, unsigned short* __restrict__ dst,
                                          int slot, int NT, int TS, int CIN, int N) {
  const int f = slot >> 6, l = slot & 63;
  const int nt = f % NT, kt = f / NT;
  const int n = nt * 16 + (l & 15), g = (l >> 4);
  unsigned short* d = dst + (size_t)f * 512 + l * 8;
#pragma unroll
  for (int j = 0; j < 8; ++j) {
    int k = kt * 32 + g * 8 + j;
    float v;
    if (TS > 0) { int tap = k / TS, c = k - tap * TS; v = (c < CIN) ? src[(tap * CIN + c) * N + n] : 0.f; }
    else        v = src[k * N + n];
    d[j] = f2bf(v);
  }
}

// fragment-region offsets in u16 units (frag = 512 u16)
#define WOFF_PNW2 0
#define WOFF_PNW3 2048
#define WOFF_MW1  10240
#define WOFF_MW2  43008
#define WOFF_MW3  59392
#define WOFF_MW4  67584
#define WOFF_MDW  75776
#define WOFF_SW1  141312
#define WOFF_SW2  153600
#define WOFF_SW3  169984
#define WOFF_SW4  178176
#define WOFF_SDW  186368
// total 492 frags = 251904 u16 = 503808 B

__global__ void prep_weights(const float* __restrict__ pw2, const float* __restrict__ pw3,
    const float* __restrict__ mw1, const float* __restrict__ mw2, const float* __restrict__ mw3,
    const float* __restrict__ mw4, const float* __restrict__ mdw,
    const float* __restrict__ sw1, const float* __restrict__ sw2, const float* __restrict__ sw3,
    const float* __restrict__ sw4, const float* __restrict__ sdw,
    unsigned short* __restrict__ wf) {
  const int slot = blockIdx.x * 256 + threadIdx.x;
  if      (slot <   256) pack_frag(pw2, wf + WOFF_PNW2, slot,          4,   0,   0,  64);
  else if (slot <  1280) pack_frag(pw3, wf + WOFF_PNW3, slot - 256,    8,   0,   0, 128);
  else if (slot <  5376) pack_frag(mw1, wf + WOFF_MW1,  slot - 1280,   8, 128, 128, 128);
  else if (slot <  7424) pack_frag(mw2, wf + WOFF_MW2,  slot - 5376,   4, 128, 128,  64);
  else if (slot <  8448) pack_frag(mw3, wf + WOFF_MW3,  slot - 7424,   4,  64,  64,  64);
  else if (slot <  9472) pack_frag(mw4, wf + WOFF_MW4,  slot - 8448,   4,  64,  64,  64);
  else if (slot < 17664) pack_frag(mdw, wf + WOFF_MDW,  slot - 9472,   8,   0,   0, 128);
  else if (slot < 19200) pack_frag(sw1, wf + WOFF_SW1,  slot - 17664,  8,  48,  36, 128);
  else if (slot < 21248) pack_frag(sw2, wf + WOFF_SW2,  slot - 19200,  4, 128, 128,  64);
  else if (slot < 22272) pack_frag(sw3, wf + WOFF_SW3,  slot - 21248,  4,  64,  64,  64);
  else if (slot < 23296) pack_frag(sw4, wf + WOFF_SW4,  slot - 22272,  4,  64,  64,  64);
  else if (slot < 31488) pack_frag(sdw, wf + WOFF_SDW,  slot - 23296,  8,   0,   0, 128);
}

// ==================== kernel 1: pointnet (unchanged structure, bf16 emb out) ====================
template<int CIN, int COUT, int SPI, int SPO, int TN, int TD>
__device__ __forceinline__ void mm_sca(const float* __restrict__ in, float* __restrict__ out,
                                       const float* __restrict__ W, int t) {
  constexpr int ND = COUT / TD;
  static_assert((NPT / TN) * ND == THREADS, "tile");
  const int n0 = (t / ND) * TN, d0 = (t % ND) * TD;
  float acc[TN][TD]{};
#pragma unroll
  for (int c = 0; c < CIN; ++c) {
    float xv[TN], wv[TD];
#pragma unroll
    for (int i = 0; i < TN; ++i) xv[i] = in[(n0 + i) * SPI + c];
#pragma unroll
    for (int j = 0; j < TD; ++j) wv[j] = W[c * COUT + d0 + j];
#pragma unroll
    for (int i = 0; i < TN; ++i)
#pragma unroll
      for (int j = 0; j < TD; ++j) acc[i][j] = fmaf(xv[i], wv[j], acc[i][j]);
  }
#pragma unroll
  for (int i = 0; i < TN; ++i)
#pragma unroll
    for (int j = 0; j < TD; ++j) out[(n0 + i) * SPO + d0 + j] = acc[i][j];
}

__global__ __launch_bounds__(THREADS)
void pointnet_kernel(const float* __restrict__ fts,
    const float* __restrict__ pw1, const float* __restrict__ pg1, const float* __restrict__ pbe1,
    const unsigned short* __restrict__ w2f, const float* __restrict__ pg2, const float* __restrict__ pbe2,
    const unsigned short* __restrict__ w3f, const float* __restrict__ pg3, const float* __restrict__ pbe3,
    const float* __restrict__ pw4, const float* __restrict__ pb4,
    unsigned short* __restrict__ emb)
{
  const int p = blockIdx.x;            // b*S + s
  const int t = threadIdx.x;
  const int l = t & 63, w = t >> 6;
  const int g = l >> 4, lc = l & 15;

  __shared__ float xin[320];
  __shared__ float x1[64 * 36];
  __shared__ unsigned short x1b[64 * 40];
  __shared__ unsigned short x2b[64 * 72];
  __shared__ float ps[256], pss[256];
  __shared__ float aA[32], bA[32];
  __shared__ float xbar[128];

  { const float* src = fts + (size_t)p * 320;
    for (int i = t; i < 320; i += THREADS) xin[i] = src[i]; }
  __syncthreads();

  mm_sca<5, 32, 5, 36, 4, 2>(xin, x1, pw1, t);
  __syncthreads();

  {
    const int c = t & 31, gr = t >> 5;
    float s = 0.f, ss = 0.f;
#pragma unroll
    for (int k = 0; k < 8; ++k) { float v = x1[(gr + 8 * k) * 36 + c]; s += v; ss = fmaf(v, v, ss); }
    ps[t] = s; pss[t] = ss;
    __syncthreads();
    if (t < 32) {
      float S1 = 0.f, S2 = 0.f;
#pragma unroll
      for (int h = 0; h < 8; ++h) { S1 += ps[h * 32 + t]; S2 += pss[h * 32 + t]; }
      float mu  = S1 * (1.f / NPT);
      float inv = rsqrtf(S2 * (1.f / NPT) - mu * mu + EPS);
      float a = inv * pg1[t];
      aA[t] = a; bA[t] = fmaf(-mu, a, pbe1[t]);
    }
    __syncthreads();
    const float a = aA[c], bb = bA[c];
#pragma unroll
    for (int k = 0; k < 8; ++k) {
      int r = gr + 8 * k;
      x1b[r * 40 + c] = f2bf(lrelu(fmaf(x1[r * 36 + c], a, bb)));
    }
  }
  __syncthreads();

  // L2 MFMA
  f4 c2[4];
#pragma unroll
  for (int mt = 0; mt < 4; ++mt) c2[mt] = f4{0.f, 0.f, 0.f, 0.f};
  {
    bf8 bfrag = *(const bf8*)(w2f + ((size_t)w * 64 + l) * 8);
#pragma unroll
    for (int mt = 0; mt < 4; ++mt) {
      bf8 afrag = *(const bf8*)(x1b + (mt * 16 + lc) * 40 + g * 8);
      c2[mt] = __builtin_amdgcn_mfma_f32_16x16x32_bf16(afrag, bfrag, c2[mt], 0, 0, 0);
    }
  }
  {
    float s = 0.f, q = 0.f;
#pragma unroll
    for (int mt = 0; mt < 4; ++mt)
#pragma unroll
      for (int r = 0; r < 4; ++r) { float v = c2[mt][r]; s += v; q = fmaf(v, v, q); }
    s += __shfl_xor(s, 16, 64); s += __shfl_xor(s, 32, 64);
    q += __shfl_xor(q, 16, 64); q += __shfl_xor(q, 32, 64);
    const int ch = w * 16 + lc;
    float mu  = s * (1.f / NPT);
    float inv = rsqrtf(q * (1.f / NPT) - mu * mu + EPS);
    float a = inv * pg2[ch];
    float bb = fmaf(-mu, a, pbe2[ch]);
#pragma unroll
    for (int mt = 0; mt < 4; ++mt)
#pragma unroll
      for (int r = 0; r < 4; ++r) {
        int row = mt * 16 + g * 4 + r;
        x2b[row * 72 + ch] = f2bf(lrelu(fmaf(c2[mt][r], a, bb)));
      }
  }
  __syncthreads();

  // L3 MFMA
  f4 c3[4][2];
#pragma unroll
  for (int mt = 0; mt < 4; ++mt)
#pragma unroll
    for (int n = 0; n < 2; ++n) c3[mt][n] = f4{0.f, 0.f, 0.f, 0.f};
  bf8 bf3[2][2];
#pragma unroll
  for (int ntl = 0; ntl < 2; ++ntl)
#pragma unroll
    for (int kt = 0; kt < 2; ++kt)
      bf3[ntl][kt] = *(const bf8*)(w3f + ((size_t)(kt * 8 + (2 * w + ntl)) * 64 + l) * 8);
#pragma unroll
  for (int mt = 0; mt < 4; ++mt)
#pragma unroll
    for (int kt = 0; kt < 2; ++kt) {
      bf8 afrag = *(const bf8*)(x2b + (mt * 16 + lc) * 72 + kt * 32 + g * 8);
#pragma unroll
      for (int ntl = 0; ntl < 2; ++ntl)
        c3[mt][ntl] = __builtin_amdgcn_mfma_f32_16x16x32_bf16(afrag, bf3[ntl][kt], c3[mt][ntl], 0, 0, 0);
    }

#pragma unroll
  for (int ntl = 0; ntl < 2; ++ntl) {
    float s = 0.f, q = 0.f;
#pragma unroll
    for (int mt = 0; mt < 4; ++mt)
#pragma unroll
      for (int r = 0; r < 4; ++r) { float v = c3[mt][ntl][r]; s += v; q = fmaf(v, v, q); }
    s += __shfl_xor(s, 16, 64); s += __shfl_xor(s, 32, 64);
    q += __shfl_xor(q, 16, 64); q += __shfl_xor(q, 32, 64);
    const int ch = w * 32 + ntl * 16 + lc;
    float mu  = s * (1.f / NPT);
    float inv = rsqrtf(q * (1.f / NPT) - mu * mu + EPS);
    float a = inv * pg3[ch];
    float bb = fmaf(-mu, a, pbe3[ch]);
    float m = 0.f;
#pragma unroll
    for (int mt = 0; mt < 4; ++mt)
#pragma unroll
      for (int r = 0; r < 4; ++r) m += lrelu(fmaf(c3[mt][ntl][r], a, bb));
    m += __shfl_xor(m, 16, 64); m += __shfl_xor(m, 32, 64);
    if (g == 0) xbar[ch] = m * (1.f / NPT);
  }
  __syncthreads();

  {
    const int d = t & 127, h = t >> 7;
    float a = 0.f;
#pragma unroll 8
    for (int c = h * 64; c < h * 64 + 64; ++c) a = fmaf(xbar[c], pw4[c * 128 + d], a);
    ps[t] = a;
  }
  __syncthreads();
  if (t < 128) emb[(size_t)p * 128 + t] = f2bf(ps[t] + ps[t + 128] + pb4[t]);
}

// ==================== kernel 2: MFMA tail, G=8 b's per block ====================
// A layout in LDS: [b_loc][9][SP] bf16, row 8 = zeros (2-tap overflow).
// Wave w owns m-tile w = rows w*16..w*16+15 = b's {2w, 2w+1}.
template<int KT, int NT, int TS, int SPI, int SPO, bool ACT>
__device__ __forceinline__ void mfma_conv(const unsigned short* __restrict__ xin,
    unsigned short* __restrict__ xout, const unsigned short* __restrict__ wfr,
    const float* __restrict__ bias, int w, int l) {
  const int g = l >> 4, lc = l & 15;
  const int arow = w * 16 + lc, abl = arow >> 3, an = arow & 7;
  f4 acc[NT];
#pragma unroll
  for (int nt = 0; nt < NT; ++nt) acc[nt] = f4{0.f, 0.f, 0.f, 0.f};
#pragma unroll
  for (int kt = 0; kt < KT; ++kt) {
    const int k0 = kt * 32 + g * 8;
    const int tap = k0 / TS, c = k0 - tap * TS;
    bf8 a = *(const bf8*)(xin + (abl * 9 + an + tap) * SPI + c);
#pragma unroll
    for (int nt = 0; nt < NT; ++nt) {
      bf8 b = *(const bf8*)(wfr + ((size_t)(kt * NT + nt) * 64 + l) * 8);
      acc[nt] = __builtin_amdgcn_mfma_f32_16x16x32_bf16(a, b, acc[nt], 0, 0, 0);
    }
  }
  const int orow0 = w * 16 + g * 4;
#pragma unroll
  for (int nt = 0; nt < NT; ++nt) {
    const float bv = bias[nt * 16 + lc];
#pragma unroll
    for (int r = 0; r < 4; ++r) {
      const int rr = orow0 + r, obl = rr >> 3, on = rr & 7;
      float v = acc[nt][r] + bv;
      if (ACT) v = lrelu(v);
      xout[(obl * 9 + on) * SPO + nt * 16 + lc] = f2bf(v);
    }
  }
}

// dense 512->128 over [8 b][8 n][64 ch] (K-split over 4 waves, partials to LDS)
__device__ __forceinline__ void mfma_dense512(const unsigned short* __restrict__ xin,
    float* __restrict__ P, const unsigned short* __restrict__ wfr, int w, int l) {
  const int g = l >> 4, lc = l & 15;
  const int bl = lc & 7;                 // rows 8-15 duplicate rows 0-7
  f4 acc[8];
#pragma unroll
  for (int nt = 0; nt < 8; ++nt) acc[nt] = f4{0.f, 0.f, 0.f, 0.f};
#pragma unroll
  for (int kt2 = 0; kt2 < 4; ++kt2) {
    const int kt = w * 4 + kt2;
    const int k0 = kt * 32 + g * 8;
    const int n = k0 >> 6, c = k0 & 63;
    bf8 a = *(const bf8*)(xin + (bl * 9 + n) * 72 + c);
#pragma unroll
    for (int nt = 0; nt < 8; ++nt) {
      bf8 b = *(const bf8*)(wfr + ((size_t)(kt * 8 + nt) * 64 + l) * 8);
      acc[nt] = __builtin_amdgcn_mfma_f32_16x16x32_bf16(a, b, acc[nt], 0, 0, 0);
    }
  }
  if (g < 2) {
#pragma unroll
    for (int nt = 0; nt < 8; ++nt)
#pragma unroll
      for (int r = 0; r < 4; ++r) {
        const int rr = g * 4 + r;       // 0..7
        P[(w * 8 + rr) * 128 + nt * 16 + lc] = acc[nt][r];
      }
  }
}

__global__ __launch_bounds__(THREADS)
void tail_mfma_kernel(const unsigned short* __restrict__ emb, const float* __restrict__ state,
    const unsigned short* __restrict__ wf,
    const float* __restrict__ mb1, const float* __restrict__ mb2, const float* __restrict__ mb3,
    const float* __restrict__ mb4, const float* __restrict__ mdb,
    const float* __restrict__ sb1, const float* __restrict__ sb2, const float* __restrict__ sb3,
    const float* __restrict__ sb4, const float* __restrict__ sdb,
    float* __restrict__ femb, float* __restrict__ semb)
{
  const int t = threadIdx.x, l = t & 63, w = t >> 6;
  const bool merge = blockIdx.x < 128;
  const int bg = merge ? blockIdx.x : blockIdx.x - 128;

  __shared__ unsigned short lds[24768];           // 49.5 KB
  unsigned short* BufX = lds;                     // [8][9][136] xin / L3-out [8][9][72] / partials
  unsigned short* BufY = lds + 9792;              // L1-out [8][9][136] / L4-out [8][9][72]
  unsigned short* BufZ = lds + 19584;             // L2-out [8][9][72]

  // zero: BufX fully; BufY row-8 (stride 136); BufZ row-8 (stride 72)
  { unsigned* z = (unsigned*)BufX; for (int i = t; i < 4896; i += THREADS) z[i] = 0; }
  for (int i = t; i < 8 * 136; i += THREADS) BufY[((i / 136) * 9 + 8) * 136 + (i % 136)] = 0;
  for (int i = t; i < 8 * 72;  i += THREADS) BufZ[((i / 72)  * 9 + 8) * 72  + (i % 72)]  = 0;

  if (merge) {
    for (int i = t; i < 1024; i += THREADS) {     // 8b x 8n x 16 chunks of 8 bf16
      int bl = i >> 7, rem = i & 127, n = rem >> 4, sl = rem & 15;
      bf8 v = *(const bf8*)(emb + (size_t)((bg * 8 + bl) * 8 + n) * 128 + sl * 8);
      *(bf8*)(BufX + (bl * 9 + n) * 136 + sl * 8) = v;
    }
  } else {
    for (int i = t; i < 2304; i += THREADS) {     // 8b x 8n x 36
      int bl = i / 288, rem = i % 288, n = rem / 36, c = rem % 36;
      BufX[(bl * 9 + n) * 48 + c] = f2bf(state[((size_t)(bg * 8 + bl) * 8 + n) * 36 + c]);
    }
  }
  __syncthreads();

  if (merge) mfma_conv<8, 8, 128, 136, 136, true>(BufX, BufY, wf + WOFF_MW1, mb1, w, l);
  else       mfma_conv<3, 8,  48,  48, 136, true>(BufX, BufY, wf + WOFF_SW1, sb1, w, l);
  __syncthreads();
  if (merge) mfma_conv<8, 4, 128, 136, 72, true>(BufY, BufZ, wf + WOFF_MW2, mb2, w, l);
  else       mfma_conv<8, 4, 128, 136, 72, true>(BufY, BufZ, wf + WOFF_SW2, sb2, w, l);
  // BufX is dead (conv1 reads done 1 barrier ago); set up L3's zero row-8 (stride 72)
  __syncthreads();
  for (int i = t; i < 8 * 72; i += THREADS) BufX[((i / 72) * 9 + 8) * 72 + (i % 72)] = 0;
  __syncthreads();
  if (merge) mfma_conv<4, 4, 64, 72, 72, true>(BufZ, BufX, wf + WOFF_MW3, mb3, w, l);
  else       mfma_conv<4, 4, 64, 72, 72, true>(BufZ, BufX, wf + WOFF_SW3, sb3, w, l);
  __syncthreads();
  if (merge) mfma_conv<4, 4, 64, 72, 72, true >(BufX, BufY, wf + WOFF_MW4, mb4, w, l);
  else       mfma_conv<4, 4, 64, 72, 72, false>(BufX, BufY, wf + WOFF_SW4, sb4, w, l);
  __syncthreads();

  float* P = (float*)lds;                         // 16 KB partials (BufX region, dead)
  mfma_dense512(BufY, P, wf + (merge ? WOFF_MDW : WOFF_SDW), w, l);
  __syncthreads();

  const float* bias = merge ? mdb : sdb;
  float* outg = (merge ? femb : semb) + (size_t)bg * 1024;
  for (int i = t; i < 1024; i += THREADS) {
    int ch = i & 127, b = i >> 7;
    outg[i] = bias[ch] + P[(0 * 8 + b) * 128 + ch] + P[(1 * 8 + b) * 128 + ch]
                       + P[(2 * 8 + b) * 128 + ch] + P[(3 * 8 + b) * 128 + ch];
  }
}

// ==================== kernel 3: control head, one wave per b ====================
template<int CIN, int COUT, bool ACT>
__device__ __forceinline__ void wave_dense(const float* __restrict__ in, float* __restrict__ out,
                                           const float* __restrict__ W, const float* __restrict__ bias, int l) {
  if constexpr (COUT >= 64) {
    constexpr int NC = COUT / 64;
    const int d0 = l * NC;
    float acc[NC];
#pragma unroll
    for (int k = 0; k < NC; ++k) acc[k] = bias[d0 + k];
#pragma unroll 4
    for (int c4 = 0; c4 < CIN / 4; ++c4) {
      v4f x4 = *(const v4f*)(in + 4 * c4);
#pragma unroll
      for (int j = 0; j < 4; ++j) {
        const float* wr = W + (4 * c4 + j) * COUT + d0;
#pragma unroll
        for (int k = 0; k < NC; ++k) acc[k] = fmaf(x4[j], wr[k], acc[k]);
      }
    }
#pragma unroll
    for (int k = 0; k < NC; ++k) out[d0 + k] = ACT ? lrelu(acc[k]) : acc[k];
  } else {
    if (l < COUT) {
      float acc = bias[l];
#pragma unroll 4
      for (int c4 = 0; c4 < CIN / 4; ++c4) {
        v4f x4 = *(const v4f*)(in + 4 * c4);
#pragma unroll
        for (int j = 0; j < 4; ++j) acc = fmaf(x4[j], W[(4 * c4 + j) * COUT + l], acc);
      }
      out[l] = ACT ? lrelu(acc) : acc;
    }
  }
}

__global__ __launch_bounds__(THREADS)
void head_kernel(const float* __restrict__ femb, const float* __restrict__ semb,
    const float* __restrict__ cw1, const float* __restrict__ cb1,
    const float* __restrict__ cw2, const float* __restrict__ cb2,
    const float* __restrict__ cw3, const float* __restrict__ cb3,
    const float* __restrict__ cw4, const float* __restrict__ cb4,
    float* __restrict__ out)
{
  const int t = threadIdx.x, l = t & 63, w = t >> 6;
  const int b = blockIdx.x * 4 + w;
  __shared__ float cat[4][256];
  __shared__ float hb[4][232];    // h1 128 | h2 64 | h3 32 (+pad)

  cat[w][l]       = femb[(size_t)b * 128 + l];
  cat[w][64 + l]  = femb[(size_t)b * 128 + 64 + l];
  cat[w][128 + l] = semb[(size_t)b * 128 + l];
  cat[w][192 + l] = semb[(size_t)b * 128 + 64 + l];
  __syncthreads();
  wave_dense<256, 128, true>(cat[w], hb[w], cw1, cb1, l);
  __syncthreads();
  wave_dense<128, 64, true>(hb[w], hb[w] + 128, cw2, cb2, l);
  __syncthreads();
  wave_dense<64, 32, true>(hb[w] + 128, hb[w] + 192, cw3, cb3, l);
  __syncthreads();
  if (l < 4) {
    float acc = cb4[l];
#pragma unroll
    for (int c = 0; c < 32; ++c) acc = fmaf(hb[w][192 + c], cw4[c * 4 + l], acc);
    out[(size_t)b * 4 + l] = (l == 0) ? 21.f / (1.f + expf(-acc)) : 6.f * tanhf(acc);
  }
}

extern "C" void kernel_launch(void* const* d_in, const int* in_sizes, int n_in,
                              void* d_out, int out_size, void* d_ws, size_t ws_size,
                              hipStream_t stream) {
  const float* p[44];
  for (int i = 0; i < 44; ++i) p[i] = (const float*)d_in[i];

  unsigned short* emb_bf = (unsigned short*)d_ws;                      // 2 MB
  float* femb = (float*)((char*)d_ws + 2097152);                       // 512 KB
  float* semb = (float*)((char*)d_ws + 2621440);                       // 512 KB
  unsigned short* wf = (unsigned short*)((char*)d_ws + 3145728);       // 504 KB

  prep_weights<<<123, THREADS, 0, stream>>>(
      p[6], p[10],
      p[16], p[18], p[20], p[22], p[24],
      p[26], p[28], p[30], p[32], p[34],
      wf);

  pointnet_kernel<<<1024 * S, THREADS, 0, stream>>>(
      p[0],
      p[2], p[4], p[5],
      wf + WOFF_PNW2, p[8], p[9],
      wf + WOFF_PNW3, p[12], p[13],
      p[14], p[15],
      emb_bf);

  tail_mfma_kernel<<<256, THREADS, 0, stream>>>(
      emb_bf, p[1], wf,
      p[17], p[19], p[21], p[23], p[25],
      p[27], p[29], p[31], p[33], p[35],
      femb, semb);

  head_kernel<<<256, THREADS, 0, stream>>>(
      femb, semb,
      p[36], p[37], p[38], p[39], p[40], p[41], p[42], p[43],
      (float*)d_out);
}

// Round 9
// 83.351 us; speedup vs baseline: 1.1545x; 1.1545x over previous
//
#include <hip/hip_runtime.h>
#include <math.h>

#define THREADS 256

constexpr int S   = 8;
constexpr int NPT = 64;
constexpr int SD  = 36;
constexpr float EPS = 1e-5f;

typedef float v4f __attribute__((ext_vector_type(4)));
typedef __attribute__((ext_vector_type(8))) short bf8;   // 8 bf16 (4 VGPR)
typedef __attribute__((ext_vector_type(4))) float f4;    // MFMA accumulator

__device__ __forceinline__ float lrelu(float x) { return x > 0.f ? x : 0.01f * x; }

// float -> bf16 round-to-nearest-even
__device__ __forceinline__ unsigned short f2bf(float x) {
  union { float f; unsigned u; } v; v.f = x;
  unsigned r = v.u + 0x7FFFu + ((v.u >> 16) & 1u);
  return (unsigned short)(r >> 16);
}

// ==================== fragment packing (one-time prep) ====================
// B-fragment: frag f = kt*NT + nt; lane l holds n = nt*16 + (l&15),
// k = kt*32 + (l>>4)*8 + j, j=0..7.
// TS>0: 2-tap conv weight [2][CIN][N], tap stride TS (zero-pad c >= CIN).
// TS==0: flat [K][N]; if CIN>0, zero-pad k >= CIN.
__device__ __forceinline__ void pack_frag(const float* __restrict__ src, unsigned short* __restrict__ dst,
                                          int slot, int NT, int TS, int CIN, int N) {
  const int f = slot >> 6, l = slot & 63;
  const int nt = f % NT, kt = f / NT;
  const int n = nt * 16 + (l & 15), g = (l >> 4);
  unsigned short* d = dst + (size_t)f * 512 + l * 8;
#pragma unroll
  for (int j = 0; j < 8; ++j) {
    int k = kt * 32 + g * 8 + j;
    float v;
    if (TS > 0) { int tap = k / TS, c = k - tap * TS; v = (c < CIN) ? src[(tap * CIN + c) * N + n] : 0.f; }
    else        v = (CIN == 0 || k < CIN) ? src[k * N + n] : 0.f;
    d[j] = f2bf(v);
  }
}

// fragment-region offsets in u16 units (frag = 512 u16)
#define WOFF_PNW1 0
#define WOFF_PNW2 1024
#define WOFF_PNW3 3072
#define WOFF_MW1  11264
#define WOFF_MW2  44032
#define WOFF_MW3  60416
#define WOFF_MW4  68608
#define WOFF_MDW  76800
#define WOFF_SW1  142336
#define WOFF_SW2  154624
#define WOFF_SW3  171008
#define WOFF_SW4  179200
#define WOFF_SDW  187392
// total 494 frags = 252928 u16 = 505856 B

// ==================== fold: W1' = pw4 @ mw1 (exact; L4 has no activation) ====================
__global__ __launch_bounds__(THREADS)
void fold_kernel(const float* __restrict__ pw4, const float* __restrict__ pb4,
                 const float* __restrict__ mw1, const float* __restrict__ mb1,
                 float* __restrict__ w1f, float* __restrict__ mb1p, float* __restrict__ mb1p7) {
  const int t = threadIdx.x, bid = blockIdx.x;
  if (bid < 256) {
    const int tap = bid >> 7, c = bid & 127;
    __shared__ float row[128];
    __shared__ float part[256];
    if (t < 128) row[t] = pw4[c * 128 + t];
    __syncthreads();
    const int n = t & 127, h = t >> 7;
    float a = 0.f;
#pragma unroll 8
    for (int d = h * 64; d < h * 64 + 64; ++d)
      a = fmaf(row[d], mw1[((size_t)tap * 128 + d) * 128 + n], a);
    part[t] = a;
    __syncthreads();
    if (t < 128) w1f[((size_t)tap * 128 + c) * 128 + t] = part[t] + part[128 + t];
  } else if (bid == 256) {
    if (t < 128) {
      float a = mb1[t];
#pragma unroll 8
      for (int k = 0; k < 128; ++k)
        a = fmaf(pb4[k], mw1[(size_t)k * 128 + t] + mw1[(size_t)(128 + k) * 128 + t], a);
      mb1p[t] = a;
    }
  } else {
    if (t < 128) {
      float a = mb1[t];
#pragma unroll 8
      for (int k = 0; k < 128; ++k) a = fmaf(pb4[k], mw1[(size_t)k * 128 + t], a);
      mb1p7[t] = a;
    }
  }
}

__global__ void prep_weights(const float* __restrict__ pw1, const float* __restrict__ pw2,
    const float* __restrict__ pw3, const float* __restrict__ w1fold,
    const float* __restrict__ mw2, const float* __restrict__ mw3,
    const float* __restrict__ mw4, const float* __restrict__ mdw,
    const float* __restrict__ sw1, const float* __restrict__ sw2, const float* __restrict__ sw3,
    const float* __restrict__ sw4, const float* __restrict__ sdw,
    unsigned short* __restrict__ wf) {
  const int slot = blockIdx.x * 256 + threadIdx.x;
  if      (slot <   128) pack_frag(pw1,    wf + WOFF_PNW1, slot,          2,   0,   5,  32);
  else if (slot <   384) pack_frag(pw2,    wf + WOFF_PNW2, slot - 128,    4,   0,   0,  64);
  else if (slot <  1408) pack_frag(pw3,    wf + WOFF_PNW3, slot - 384,    8,   0,   0, 128);
  else if (slot <  5504) pack_frag(w1fold, wf + WOFF_MW1,  slot - 1408,   8, 128, 128, 128);
  else if (slot <  7552) pack_frag(mw2,    wf + WOFF_MW2,  slot - 5504,   4, 128, 128,  64);
  else if (slot <  8576) pack_frag(mw3,    wf + WOFF_MW3,  slot - 7552,   4,  64,  64,  64);
  else if (slot <  9600) pack_frag(mw4,    wf + WOFF_MW4,  slot - 8576,   4,  64,  64,  64);
  else if (slot < 17792) pack_frag(mdw,    wf + WOFF_MDW,  slot - 9600,   8,   0,   0, 128);
  else if (slot < 19328) pack_frag(sw1,    wf + WOFF_SW1,  slot - 17792,  8,  48,  36, 128);
  else if (slot < 21376) pack_frag(sw2,    wf + WOFF_SW2,  slot - 19328,  4, 128, 128,  64);
  else if (slot < 22400) pack_frag(sw3,    wf + WOFF_SW3,  slot - 21376,  4,  64,  64,  64);
  else if (slot < 23424) pack_frag(sw4,    wf + WOFF_SW4,  slot - 22400,  4,  64,  64,  64);
  else if (slot < 31616) pack_frag(sdw,    wf + WOFF_SDW,  slot - 23424,  8,   0,   0, 128);
}

// ==================== kernel 1: pointnet, all-MFMA, all norms in-register ====================
// Ends at xbar (L4 folded into the tail's conv1); writes 128 bf16 per (b,s).
__global__ __launch_bounds__(THREADS)
void pointnet_kernel(const float* __restrict__ fts,
    const unsigned short* __restrict__ w1f, const float* __restrict__ pg1, const float* __restrict__ pbe1,
    const unsigned short* __restrict__ w2f, const float* __restrict__ pg2, const float* __restrict__ pbe2,
    const unsigned short* __restrict__ w3f, const float* __restrict__ pg3, const float* __restrict__ pbe3,
    unsigned short* __restrict__ xbar_out)
{
  const int p = blockIdx.x;            // b*S + s
  const int t = threadIdx.x;
  const int l = t & 63, w = t >> 6;
  const int g = l >> 4, lc = l & 15;

  __shared__ unsigned short xinb[64 * 40];   // input bf16, K zero-padded to 32
  __shared__ unsigned short x1b[64 * 40];    // L1 normed (ch 0..31)
  __shared__ unsigned short x2b[64 * 72];    // L2 normed (ch 0..63)

  // stage input: one pass writes data cols 0..4 (bf16) and zeros 5..39, as u32 pairs
  {
    const float* src = fts + (size_t)p * 320;
    unsigned* xz = (unsigned*)xinb;
    for (int i = t; i < 1280; i += THREADS) {
      int row = i / 20, cp = i % 20;
      int c0 = 2 * cp;
      unsigned short lo = (c0 < 5) ? f2bf(src[row * 5 + c0]) : (unsigned short)0;
      unsigned short hi = (c0 + 1 < 5) ? f2bf(src[row * 5 + c0 + 1]) : (unsigned short)0;
      xz[i] = (unsigned)lo | ((unsigned)hi << 16);
    }
  }
  __syncthreads();

  // ---- L1 MFMA [64x32(k,pad5)]@[32x32]; waves 0,1 own 16 channels each ----
  if (w < 2) {
    f4 c1[4];
#pragma unroll
    for (int mt = 0; mt < 4; ++mt) c1[mt] = f4{0.f, 0.f, 0.f, 0.f};
    bf8 bfrag = *(const bf8*)(w1f + ((size_t)w * 64 + l) * 8);
#pragma unroll
    for (int mt = 0; mt < 4; ++mt) {
      bf8 afrag = *(const bf8*)(xinb + (mt * 16 + lc) * 40 + g * 8);
      c1[mt] = __builtin_amdgcn_mfma_f32_16x16x32_bf16(afrag, bfrag, c1[mt], 0, 0, 0);
    }
    float s = 0.f, q = 0.f;
#pragma unroll
    for (int mt = 0; mt < 4; ++mt)
#pragma unroll
      for (int r = 0; r < 4; ++r) { float v = c1[mt][r]; s += v; q = fmaf(v, v, q); }
    s += __shfl_xor(s, 16, 64); s += __shfl_xor(s, 32, 64);
    q += __shfl_xor(q, 16, 64); q += __shfl_xor(q, 32, 64);
    const int ch = w * 16 + lc;
    float mu  = s * (1.f / NPT);
    float inv = rsqrtf(q * (1.f / NPT) - mu * mu + EPS);
    float a = inv * pg1[ch];
    float bb = fmaf(-mu, a, pbe1[ch]);
#pragma unroll
    for (int mt = 0; mt < 4; ++mt)
#pragma unroll
      for (int r = 0; r < 4; ++r) {
        int row = mt * 16 + g * 4 + r;
        x1b[row * 40 + ch] = f2bf(lrelu(fmaf(c1[mt][r], a, bb)));
      }
  }
  __syncthreads();

  // ---- L2 MFMA [64x32]@[32x64]; wave w owns channels 16w..16w+15 ----
  f4 c2[4];
#pragma unroll
  for (int mt = 0; mt < 4; ++mt) c2[mt] = f4{0.f, 0.f, 0.f, 0.f};
  {
    bf8 bfrag = *(const bf8*)(w2f + ((size_t)w * 64 + l) * 8);
#pragma unroll
    for (int mt = 0; mt < 4; ++mt) {
      bf8 afrag = *(const bf8*)(x1b + (mt * 16 + lc) * 40 + g * 8);
      c2[mt] = __builtin_amdgcn_mfma_f32_16x16x32_bf16(afrag, bfrag, c2[mt], 0, 0, 0);
    }
  }
  {
    float s = 0.f, q = 0.f;
#pragma unroll
    for (int mt = 0; mt < 4; ++mt)
#pragma unroll
      for (int r = 0; r < 4; ++r) { float v = c2[mt][r]; s += v; q = fmaf(v, v, q); }
    s += __shfl_xor(s, 16, 64); s += __shfl_xor(s, 32, 64);
    q += __shfl_xor(q, 16, 64); q += __shfl_xor(q, 32, 64);
    const int ch = w * 16 + lc;
    float mu  = s * (1.f / NPT);
    float inv = rsqrtf(q * (1.f / NPT) - mu * mu + EPS);
    float a = inv * pg2[ch];
    float bb = fmaf(-mu, a, pbe2[ch]);
#pragma unroll
    for (int mt = 0; mt < 4; ++mt)
#pragma unroll
      for (int r = 0; r < 4; ++r) {
        int row = mt * 16 + g * 4 + r;
        x2b[row * 72 + ch] = f2bf(lrelu(fmaf(c2[mt][r], a, bb)));
      }
  }
  __syncthreads();

  // ---- L3 MFMA [64x64]@[64x128]; wave w owns channels 32w..32w+31 ----
  f4 c3[4][2];
#pragma unroll
  for (int mt = 0; mt < 4; ++mt)
#pragma unroll
    for (int n = 0; n < 2; ++n) c3[mt][n] = f4{0.f, 0.f, 0.f, 0.f};
  bf8 bf3[2][2];
#pragma unroll
  for (int ntl = 0; ntl < 2; ++ntl)
#pragma unroll
    for (int kt = 0; kt < 2; ++kt)
      bf3[ntl][kt] = *(const bf8*)(w3f + ((size_t)(kt * 8 + (2 * w + ntl)) * 64 + l) * 8);
#pragma unroll
  for (int mt = 0; mt < 4; ++mt)
#pragma unroll
    for (int kt = 0; kt < 2; ++kt) {
      bf8 afrag = *(const bf8*)(x2b + (mt * 16 + lc) * 72 + kt * 32 + g * 8);
#pragma unroll
      for (int ntl = 0; ntl < 2; ++ntl)
        c3[mt][ntl] = __builtin_amdgcn_mfma_f32_16x16x32_bf16(afrag, bf3[ntl][kt], c3[mt][ntl], 0, 0, 0);
    }

  // ---- inorm3 + lrelu + mean over n, in-register; write xbar bf16 to global ----
#pragma unroll
  for (int ntl = 0; ntl < 2; ++ntl) {
    float s = 0.f, q = 0.f;
#pragma unroll
    for (int mt = 0; mt < 4; ++mt)
#pragma unroll
      for (int r = 0; r < 4; ++r) { float v = c3[mt][ntl][r]; s += v; q = fmaf(v, v, q); }
    s += __shfl_xor(s, 16, 64); s += __shfl_xor(s, 32, 64);
    q += __shfl_xor(q, 16, 64); q += __shfl_xor(q, 32, 64);
    const int ch = w * 32 + ntl * 16 + lc;
    float mu  = s * (1.f / NPT);
    float inv = rsqrtf(q * (1.f / NPT) - mu * mu + EPS);
    float a = inv * pg3[ch];
    float bb = fmaf(-mu, a, pbe3[ch]);
    float m = 0.f;
#pragma unroll
    for (int mt = 0; mt < 4; ++mt)
#pragma unroll
      for (int r = 0; r < 4; ++r) m += lrelu(fmaf(c3[mt][ntl][r], a, bb));
    m += __shfl_xor(m, 16, 64); m += __shfl_xor(m, 32, 64);
    if (g == 0) xbar_out[(size_t)p * 128 + ch] = f2bf(m * (1.f / NPT));
  }
}

// ==================== kernel 2: MFMA tail, G=8 b's per block ====================
// A layout in LDS: [b_loc][9][SP] bf16, row 8 = zeros (2-tap overflow).
// bias7 applies to output rows with n==7 (folded-conv1 edge); pass bias7==bias otherwise.
template<int KT, int NT, int TS, int SPI, int SPO, bool ACT>
__device__ __forceinline__ void mfma_conv(const unsigned short* __restrict__ xin,
    unsigned short* __restrict__ xout, const unsigned short* __restrict__ wfr,
    const float* __restrict__ bias, const float* __restrict__ bias7, int w, int l) {
  const int g = l >> 4, lc = l & 15;
  const int arow = w * 16 + lc, abl = arow >> 3, an = arow & 7;
  f4 acc[NT];
#pragma unroll
  for (int nt = 0; nt < NT; ++nt) acc[nt] = f4{0.f, 0.f, 0.f, 0.f};
#pragma unroll
  for (int kt = 0; kt < KT; ++kt) {
    const int k0 = kt * 32 + g * 8;
    const int tap = k0 / TS, c = k0 - tap * TS;
    bf8 a = *(const bf8*)(xin + (abl * 9 + an + tap) * SPI + c);
#pragma unroll
    for (int nt = 0; nt < NT; ++nt) {
      bf8 b = *(const bf8*)(wfr + ((size_t)(kt * NT + nt) * 64 + l) * 8);
      acc[nt] = __builtin_amdgcn_mfma_f32_16x16x32_bf16(a, b, acc[nt], 0, 0, 0);
    }
  }
  const int orow0 = w * 16 + g * 4;
#pragma unroll
  for (int nt = 0; nt < NT; ++nt) {
    const float bv  = bias[nt * 16 + lc];
    const float bv7 = bias7[nt * 16 + lc];
#pragma unroll
    for (int r = 0; r < 4; ++r) {
      const int rr = orow0 + r, obl = rr >> 3, on = rr & 7;
      float v = acc[nt][r] + (on == 7 ? bv7 : bv);
      if (ACT) v = lrelu(v);
      xout[(obl * 9 + on) * SPO + nt * 16 + lc] = f2bf(v);
    }
  }
}

// dense 512->128 over [8 b][8 n][64 ch] (K-split over 4 waves, partials to LDS)
__device__ __forceinline__ void mfma_dense512(const unsigned short* __restrict__ xin,
    float* __restrict__ P, const unsigned short* __restrict__ wfr, int w, int l) {
  const int g = l >> 4, lc = l & 15;
  const int bl = lc & 7;                 // rows 8-15 duplicate rows 0-7
  f4 acc[8];
#pragma unroll
  for (int nt = 0; nt < 8; ++nt) acc[nt] = f4{0.f, 0.f, 0.f, 0.f};
#pragma unroll
  for (int kt2 = 0; kt2 < 4; ++kt2) {
    const int kt = w * 4 + kt2;
    const int k0 = kt * 32 + g * 8;
    const int n = k0 >> 6, c = k0 & 63;
    bf8 a = *(const bf8*)(xin + (bl * 9 + n) * 72 + c);
#pragma unroll
    for (int nt = 0; nt < 8; ++nt) {
      bf8 b = *(const bf8*)(wfr + ((size_t)(kt * 8 + nt) * 64 + l) * 8);
      acc[nt] = __builtin_amdgcn_mfma_f32_16x16x32_bf16(a, b, acc[nt], 0, 0, 0);
    }
  }
  if (g < 2) {
#pragma unroll
    for (int nt = 0; nt < 8; ++nt)
#pragma unroll
      for (int r = 0; r < 4; ++r) {
        const int rr = g * 4 + r;       // 0..7
        P[(w * 8 + rr) * 128 + nt * 16 + lc] = acc[nt][r];
      }
  }
}

__global__ __launch_bounds__(THREADS)
void tail_mfma_kernel(const unsigned short* __restrict__ xbar, const float* __restrict__ state,
    const unsigned short* __restrict__ wf,
    const float* __restrict__ mb1p, const float* __restrict__ mb1p7,
    const float* __restrict__ mb2, const float* __restrict__ mb3,
    const float* __restrict__ mb4, const float* __restrict__ mdb,
    const float* __restrict__ sb1, const float* __restrict__ sb2, const float* __restrict__ sb3,
    const float* __restrict__ sb4, const float* __restrict__ sdb,
    float* __restrict__ femb, float* __restrict__ semb)
{
  const int t = threadIdx.x, l = t & 63, w = t >> 6;
  const bool merge = blockIdx.x < 128;
  const int bg = merge ? blockIdx.x : blockIdx.x - 128;

  __shared__ unsigned short lds[24768];           // 49.5 KB
  unsigned short* BufX = lds;                     // [8][9][136] xin / L3-out [8][9][72] / partials
  unsigned short* BufY = lds + 9792;              // L1-out [8][9][136] / L4-out [8][9][72]
  unsigned short* BufZ = lds + 19584;             // L2-out [8][9][72]

  // zero: BufX fully; BufY row-8 (stride 136); BufZ row-8 (stride 72)
  { unsigned* z = (unsigned*)BufX; for (int i = t; i < 4896; i += THREADS) z[i] = 0; }
  for (int i = t; i < 8 * 136; i += THREADS) BufY[((i / 136) * 9 + 8) * 136 + (i % 136)] = 0;
  for (int i = t; i < 8 * 72;  i += THREADS) BufZ[((i / 72)  * 9 + 8) * 72  + (i % 72)]  = 0;

  if (merge) {
    for (int i = t; i < 1024; i += THREADS) {     // 8b x 8n x 16 chunks of 8 bf16
      int bl = i >> 7, rem = i & 127, n = rem >> 4, sl = rem & 15;
      bf8 v = *(const bf8*)(xbar + (size_t)((bg * 8 + bl) * 8 + n) * 128 + sl * 8);
      *(bf8*)(BufX + (bl * 9 + n) * 136 + sl * 8) = v;
    }
  } else {
    for (int i = t; i < 2304; i += THREADS) {     // 8b x 8n x 36
      int bl = i / 288, rem = i % 288, n = rem / 36, c = rem % 36;
      BufX[(bl * 9 + n) * 48 + c] = f2bf(state[((size_t)(bg * 8 + bl) * 8 + n) * 36 + c]);
    }
  }
  __syncthreads();

  if (merge) mfma_conv<8, 8, 128, 136, 136, true>(BufX, BufY, wf + WOFF_MW1, mb1p, mb1p7, w, l);
  else       mfma_conv<3, 8,  48,  48, 136, true>(BufX, BufY, wf + WOFF_SW1, sb1, sb1, w, l);
  __syncthreads();
  if (merge) mfma_conv<8, 4, 128, 136, 72, true>(BufY, BufZ, wf + WOFF_MW2, mb2, mb2, w, l);
  else       mfma_conv<8, 4, 128, 136, 72, true>(BufY, BufZ, wf + WOFF_SW2, sb2, sb2, w, l);
  // BufX is dead; set up L3's zero row-8 (stride 72)
  __syncthreads();
  for (int i = t; i < 8 * 72; i += THREADS) BufX[((i / 72) * 9 + 8) * 72 + (i % 72)] = 0;
  __syncthreads();
  if (merge) mfma_conv<4, 4, 64, 72, 72, true>(BufZ, BufX, wf + WOFF_MW3, mb3, mb3, w, l);
  else       mfma_conv<4, 4, 64, 72, 72, true>(BufZ, BufX, wf + WOFF_SW3, sb3, sb3, w, l);
  __syncthreads();
  if (merge) mfma_conv<4, 4, 64, 72, 72, true >(BufX, BufY, wf + WOFF_MW4, mb4, mb4, w, l);
  else       mfma_conv<4, 4, 64, 72, 72, false>(BufX, BufY, wf + WOFF_SW4, sb4, sb4, w, l);
  __syncthreads();

  float* P = (float*)lds;                         // 16 KB partials (BufX region, dead)
  mfma_dense512(BufY, P, wf + (merge ? WOFF_MDW : WOFF_SDW), w, l);
  __syncthreads();

  const float* bias = merge ? mdb : sdb;
  float* outg = (merge ? femb : semb) + (size_t)bg * 1024;
  for (int i = t; i < 1024; i += THREADS) {
    int ch = i & 127, b = i >> 7;
    outg[i] = bias[ch] + P[(0 * 8 + b) * 128 + ch] + P[(1 * 8 + b) * 128 + ch]
                       + P[(2 * 8 + b) * 128 + ch] + P[(3 * 8 + b) * 128 + ch];
  }
}

// ==================== kernel 3: control head, one wave per b ====================
template<int CIN, int COUT, bool ACT>
__device__ __forceinline__ void wave_dense(const float* __restrict__ in, float* __restrict__ out,
                                           const float* __restrict__ W, const float* __restrict__ bias, int l) {
  if constexpr (COUT >= 64) {
    constexpr int NC = COUT / 64;
    const int d0 = l * NC;
    float acc[NC];
#pragma unroll
    for (int k = 0; k < NC; ++k) acc[k] = bias[d0 + k];
#pragma unroll 4
    for (int c4 = 0; c4 < CIN / 4; ++c4) {
      v4f x4 = *(const v4f*)(in + 4 * c4);
#pragma unroll
      for (int j = 0; j < 4; ++j) {
        const float* wr = W + (4 * c4 + j) * COUT + d0;
#pragma unroll
        for (int k = 0; k < NC; ++k) acc[k] = fmaf(x4[j], wr[k], acc[k]);
      }
    }
#pragma unroll
    for (int k = 0; k < NC; ++k) out[d0 + k] = ACT ? lrelu(acc[k]) : acc[k];
  } else {
    if (l < COUT) {
      float acc = bias[l];
#pragma unroll 4
      for (int c4 = 0; c4 < CIN / 4; ++c4) {
        v4f x4 = *(const v4f*)(in + 4 * c4);
#pragma unroll
        for (int j = 0; j < 4; ++j) acc = fmaf(x4[j], W[(4 * c4 + j) * COUT + l], acc);
      }
      out[l] = ACT ? lrelu(acc) : acc;
    }
  }
}

__global__ __launch_bounds__(THREADS)
void head_kernel(const float* __restrict__ femb, const float* __restrict__ semb,
    const float* __restrict__ cw1, const float* __restrict__ cb1,
    const float* __restrict__ cw2, const float* __restrict__ cb2,
    const float* __restrict__ cw3, const float* __restrict__ cb3,
    const float* __restrict__ cw4, const float* __restrict__ cb4,
    float* __restrict__ out)
{
  const int t = threadIdx.x, l = t & 63, w = t >> 6;
  const int b = blockIdx.x * 4 + w;
  __shared__ float cat[4][256];
  __shared__ float hb[4][232];    // h1 128 | h2 64 | h3 32 (+pad)

  cat[w][l]       = femb[(size_t)b * 128 + l];
  cat[w][64 + l]  = femb[(size_t)b * 128 + 64 + l];
  cat[w][128 + l] = semb[(size_t)b * 128 + l];
  cat[w][192 + l] = semb[(size_t)b * 128 + 64 + l];
  __syncthreads();
  wave_dense<256, 128, true>(cat[w], hb[w], cw1, cb1, l);
  __syncthreads();
  wave_dense<128, 64, true>(hb[w], hb[w] + 128, cw2, cb2, l);
  __syncthreads();
  wave_dense<64, 32, true>(hb[w] + 128, hb[w] + 192, cw3, cb3, l);
  __syncthreads();
  if (l < 4) {
    float acc = cb4[l];
#pragma unroll
    for (int c = 0; c < 32; ++c) acc = fmaf(hb[w][192 + c], cw4[c * 4 + l], acc);
    out[(size_t)b * 4 + l] = (l == 0) ? 21.f / (1.f + expf(-acc)) : 6.f * tanhf(acc);
  }
}

extern "C" void kernel_launch(void* const* d_in, const int* in_sizes, int n_in,
                              void* d_out, int out_size, void* d_ws, size_t ws_size,
                              hipStream_t stream) {
  const float* p[44];
  for (int i = 0; i < 44; ++i) p[i] = (const float*)d_in[i];

  unsigned short* xbar_bf = (unsigned short*)d_ws;                     // 2 MB
  float* femb  = (float*)((char*)d_ws + 2097152);                      // 512 KB
  float* w1fld = (float*)((char*)d_ws + 2097152);                      // 128 KB (dead before femb written)
  float* semb  = (float*)((char*)d_ws + 2621440);                      // 512 KB
  unsigned short* wf = (unsigned short*)((char*)d_ws + 3145728);       // 505856 B
  float* mb1p  = (float*)((char*)d_ws + 3651584);                      // 512 B
  float* mb1p7 = (float*)((char*)d_ws + 3652096);                      // 512 B

  fold_kernel<<<258, THREADS, 0, stream>>>(p[14], p[15], p[16], p[17], w1fld, mb1p, mb1p7);

  prep_weights<<<124, THREADS, 0, stream>>>(
      p[2], p[6], p[10], w1fld,
      p[18], p[20], p[22], p[24],
      p[26], p[28], p[30], p[32], p[34],
      wf);

  pointnet_kernel<<<1024 * S, THREADS, 0, stream>>>(
      p[0],
      wf + WOFF_PNW1, p[4], p[5],
      wf + WOFF_PNW2, p[8], p[9],
      wf + WOFF_PNW3, p[12], p[13],
      xbar_bf);

  tail_mfma_kernel<<<256, THREADS, 0, stream>>>(
      xbar_bf, p[1], wf,
      mb1p, mb1p7, p[19], p[21], p[23], p[25],
      p[27], p[29], p[31], p[33], p[35],
      femb, semb);

  head_kernel<<<256, THREADS, 0, stream>>>(
      femb, semb,
      p[36], p[37], p[38], p[39], p[40], p[41], p[42], p[43],
      (float*)d_out);
}

// Round 10
// 79.263 us; speedup vs baseline: 1.2140x; 1.0516x over previous
//
#include <hip/hip_runtime.h>
#include <hip/hip_bf16.h>
#include <math.h>

#define THREADS 256

constexpr int S   = 8;
constexpr int NPT = 64;
constexpr int SD  = 36;
constexpr float EPS = 1e-5f;

typedef float v4f __attribute__((ext_vector_type(4)));
typedef __attribute__((ext_vector_type(8))) short bf8;   // 8 bf16 (4 VGPR)
typedef __attribute__((ext_vector_type(4))) float f4;    // MFMA accumulator

__device__ __forceinline__ float lrelu(float x) { return fmaxf(x, 0.01f * x); }

// float -> bf16 via native HW conversion (RNE)
__device__ __forceinline__ unsigned short f2bf(float x) {
  return __builtin_bit_cast(unsigned short, __float2bfloat16(x));
}

// ==================== fragment packing (one-time prep) ====================
// B-fragment: frag f = kt*NT + nt; lane l holds n = nt*16 + (l&15),
// k = kt*32 + (l>>4)*8 + j, j=0..7.
// TS>0: 2-tap conv weight [2][CIN][N], tap stride TS (zero-pad c >= CIN).
// TS==0: flat [K][N]; if CIN>0, zero-pad k >= CIN.
__device__ __forceinline__ void pack_frag(const float* __restrict__ src, unsigned short* __restrict__ dst,
                                          int slot, int NT, int TS, int CIN, int N) {
  const int f = slot >> 6, l = slot & 63;
  const int nt = f % NT, kt = f / NT;
  const int n = nt * 16 + (l & 15), g = (l >> 4);
  unsigned short* d = dst + (size_t)f * 512 + l * 8;
#pragma unroll
  for (int j = 0; j < 8; ++j) {
    int k = kt * 32 + g * 8 + j;
    float v;
    if (TS > 0) { int tap = k / TS, c = k - tap * TS; v = (c < CIN) ? src[(tap * CIN + c) * N + n] : 0.f; }
    else        v = (CIN == 0 || k < CIN) ? src[k * N + n] : 0.f;
    d[j] = f2bf(v);
  }
}

// MW1 fragments with the L4 fold done on the fly:
// W1'[tap][c][n] = sum_d pw4[c][d] * mw1[tap][d][n]   (exact; L4 has no activation)
__device__ __forceinline__ void pack_frag_fold(const float* __restrict__ pw4,
    const float* __restrict__ mw1, unsigned short* __restrict__ dst, int slot) {
  const int f = slot >> 6, l = slot & 63;     // NT = 8
  const int nt = f & 7, kt = f >> 3;
  const int n = nt * 16 + (l & 15), g = l >> 4;
  const int k0 = kt * 32 + g * 8;
  const int tap = k0 >> 7, c0 = k0 & 127;     // 8 consecutive c, single tap (k0 % 8 == 0)
  float acc[8] = {};
  const float* mcol = mw1 + (size_t)tap * 128 * 128 + n;   // mw1[tap][d][n], d stride 128
  const float* pr   = pw4 + (size_t)c0 * 128;              // pw4[c0+j][d]
  for (int d = 0; d < 128; ++d) {
    float m = mcol[(size_t)d * 128];
#pragma unroll
    for (int j = 0; j < 8; ++j) acc[j] = fmaf(pr[j * 128 + d], m, acc[j]);
  }
  unsigned short* dd = dst + (size_t)f * 512 + l * 8;
#pragma unroll
  for (int j = 0; j < 8; ++j) dd[j] = f2bf(acc[j]);
}

// fragment-region offsets in u16 units (frag = 512 u16)
#define WOFF_PNW1 0
#define WOFF_PNW2 1024
#define WOFF_PNW3 3072
#define WOFF_MW1  11264
#define WOFF_MW2  44032
#define WOFF_MW3  60416
#define WOFF_MW4  68608
#define WOFF_MDW  76800
#define WOFF_SW1  142336
#define WOFF_SW2  154624
#define WOFF_SW3  171008
#define WOFF_SW4  179200
#define WOFF_SDW  187392
// total 494 frags = 252928 u16 = 505856 B

__global__ void prep_weights(const float* __restrict__ pw1, const float* __restrict__ pw2,
    const float* __restrict__ pw3,
    const float* __restrict__ pw4, const float* __restrict__ pb4,
    const float* __restrict__ mw1, const float* __restrict__ mb1,
    const float* __restrict__ mw2, const float* __restrict__ mw3,
    const float* __restrict__ mw4, const float* __restrict__ mdw,
    const float* __restrict__ sw1, const float* __restrict__ sw2, const float* __restrict__ sw3,
    const float* __restrict__ sw4, const float* __restrict__ sdw,
    unsigned short* __restrict__ wf, float* __restrict__ mb1p, float* __restrict__ mb1p7) {
  const int slot = blockIdx.x * 256 + threadIdx.x;
  if      (slot <   128) pack_frag(pw1,    wf + WOFF_PNW1, slot,          2,   0,   5,  32);
  else if (slot <   384) pack_frag(pw2,    wf + WOFF_PNW2, slot - 128,    4,   0,   0,  64);
  else if (slot <  1408) pack_frag(pw3,    wf + WOFF_PNW3, slot - 384,    8,   0,   0, 128);
  else if (slot <  5504) pack_frag_fold(pw4, mw1, wf + WOFF_MW1, slot - 1408);
  else if (slot <  7552) pack_frag(mw2,    wf + WOFF_MW2,  slot - 5504,   4, 128, 128,  64);
  else if (slot <  8576) pack_frag(mw3,    wf + WOFF_MW3,  slot - 7552,   4,  64,  64,  64);
  else if (slot <  9600) pack_frag(mw4,    wf + WOFF_MW4,  slot - 8576,   4,  64,  64,  64);
  else if (slot < 17792) pack_frag(mdw,    wf + WOFF_MDW,  slot - 9600,   8,   0,   0, 128);
  else if (slot < 19328) pack_frag(sw1,    wf + WOFF_SW1,  slot - 17792,  8,  48,  36, 128);
  else if (slot < 21376) pack_frag(sw2,    wf + WOFF_SW2,  slot - 19328,  4, 128, 128,  64);
  else if (slot < 22400) pack_frag(sw3,    wf + WOFF_SW3,  slot - 21376,  4,  64,  64,  64);
  else if (slot < 23424) pack_frag(sw4,    wf + WOFF_SW4,  slot - 22400,  4,  64,  64,  64);
  else if (slot < 31616) pack_frag(sdw,    wf + WOFF_SDW,  slot - 23424,  8,   0,   0, 128);
  else if (slot < 31744) {                  // conv1 bias, rows n<7 (both taps see pb4)
    const int n = slot - 31616;
    float a = mb1[n];
    for (int d = 0; d < 128; ++d)
      a = fmaf(pb4[d], mw1[(size_t)d * 128 + n] + mw1[(size_t)(128 + d) * 128 + n], a);
    mb1p[n] = a;
  } else if (slot < 31872) {                // conv1 bias, row n==7 (tap1 input is zero pad)
    const int n = slot - 31744;
    float a = mb1[n];
    for (int d = 0; d < 128; ++d) a = fmaf(pb4[d], mw1[(size_t)d * 128 + n], a);
    mb1p7[n] = a;
  }
}

// ==================== kernel 1: pointnet, all-MFMA, all norms in-register ====================
// Ends at xbar (L4 folded into the tail's conv1); writes 128 bf16 per (b,s).
__global__ __launch_bounds__(THREADS)
void pointnet_kernel(const float* __restrict__ fts,
    const unsigned short* __restrict__ w1f, const float* __restrict__ pg1, const float* __restrict__ pbe1,
    const unsigned short* __restrict__ w2f, const float* __restrict__ pg2, const float* __restrict__ pbe2,
    const unsigned short* __restrict__ w3f, const float* __restrict__ pg3, const float* __restrict__ pbe3,
    unsigned short* __restrict__ xbar_out)
{
  const int p = blockIdx.x;            // b*S + s
  const int t = threadIdx.x;
  const int l = t & 63, w = t >> 6;
  const int g = l >> 4, lc = l & 15;

  __shared__ unsigned short xinb[64 * 40];   // input bf16, K zero-padded to 32 (cols 32..39 unused)
  __shared__ unsigned short x1b[64 * 40];    // L1 normed (ch 0..31)
  __shared__ unsigned short x2b[64 * 72];    // L2 normed (ch 0..63)

  // stage input: thread t owns row t>>2, u32 column slot (t&3)+4k, k=0..3.
  // only k=0, (t&3)<3 carries data (ch 0..4); the rest is the K-pad zeros.
  {
    const float* src = fts + (size_t)p * 320;
    unsigned* xz = (unsigned*)xinb;
    const int row = t >> 2, cp = t & 3;
    const float* sr = src + row * 5;
    unsigned v0 = 0u;
    if (cp == 0)      v0 = (unsigned)f2bf(sr[0]) | ((unsigned)f2bf(sr[1]) << 16);
    else if (cp == 1) v0 = (unsigned)f2bf(sr[2]) | ((unsigned)f2bf(sr[3]) << 16);
    else if (cp == 2) v0 = (unsigned)f2bf(sr[4]);
    unsigned* xr = xz + row * 20;
    xr[cp]      = v0;
    xr[cp + 4]  = 0u;
    xr[cp + 8]  = 0u;
    xr[cp + 12] = 0u;
  }
  __syncthreads();

  // ---- L1 MFMA [64x32(k,pad5)]@[32x32]; waves 0,1 own 16 channels each ----
  if (w < 2) {
    f4 c1[4];
#pragma unroll
    for (int mt = 0; mt < 4; ++mt) c1[mt] = f4{0.f, 0.f, 0.f, 0.f};
    bf8 bfrag = *(const bf8*)(w1f + ((size_t)w * 64 + l) * 8);
#pragma unroll
    for (int mt = 0; mt < 4; ++mt) {
      bf8 afrag = *(const bf8*)(xinb + (mt * 16 + lc) * 40 + g * 8);
      c1[mt] = __builtin_amdgcn_mfma_f32_16x16x32_bf16(afrag, bfrag, c1[mt], 0, 0, 0);
    }
    float s = 0.f, q = 0.f;
#pragma unroll
    for (int mt = 0; mt < 4; ++mt)
#pragma unroll
      for (int r = 0; r < 4; ++r) { float v = c1[mt][r]; s += v; q = fmaf(v, v, q); }
    s += __shfl_xor(s, 16, 64); s += __shfl_xor(s, 32, 64);
    q += __shfl_xor(q, 16, 64); q += __shfl_xor(q, 32, 64);
    const int ch = w * 16 + lc;
    float mu  = s * (1.f / NPT);
    float inv = rsqrtf(q * (1.f / NPT) - mu * mu + EPS);
    float a = inv * pg1[ch];
    float bb = fmaf(-mu, a, pbe1[ch]);
#pragma unroll
    for (int mt = 0; mt < 4; ++mt)
#pragma unroll
      for (int r = 0; r < 4; ++r) {
        int row = mt * 16 + g * 4 + r;
        x1b[row * 40 + ch] = f2bf(lrelu(fmaf(c1[mt][r], a, bb)));
      }
  }
  __syncthreads();

  // ---- L2 MFMA [64x32]@[32x64]; wave w owns channels 16w..16w+15 ----
  f4 c2[4];
#pragma unroll
  for (int mt = 0; mt < 4; ++mt) c2[mt] = f4{0.f, 0.f, 0.f, 0.f};
  {
    bf8 bfrag = *(const bf8*)(w2f + ((size_t)w * 64 + l) * 8);
#pragma unroll
    for (int mt = 0; mt < 4; ++mt) {
      bf8 afrag = *(const bf8*)(x1b + (mt * 16 + lc) * 40 + g * 8);
      c2[mt] = __builtin_amdgcn_mfma_f32_16x16x32_bf16(afrag, bfrag, c2[mt], 0, 0, 0);
    }
  }
  {
    float s = 0.f, q = 0.f;
#pragma unroll
    for (int mt = 0; mt < 4; ++mt)
#pragma unroll
      for (int r = 0; r < 4; ++r) { float v = c2[mt][r]; s += v; q = fmaf(v, v, q); }
    s += __shfl_xor(s, 16, 64); s += __shfl_xor(s, 32, 64);
    q += __shfl_xor(q, 16, 64); q += __shfl_xor(q, 32, 64);
    const int ch = w * 16 + lc;
    float mu  = s * (1.f / NPT);
    float inv = rsqrtf(q * (1.f / NPT) - mu * mu + EPS);
    float a = inv * pg2[ch];
    float bb = fmaf(-mu, a, pbe2[ch]);
#pragma unroll
    for (int mt = 0; mt < 4; ++mt)
#pragma unroll
      for (int r = 0; r < 4; ++r) {
        int row = mt * 16 + g * 4 + r;
        x2b[row * 72 + ch] = f2bf(lrelu(fmaf(c2[mt][r], a, bb)));
      }
  }
  __syncthreads();

  // ---- L3 MFMA [64x64]@[64x128]; wave w owns channels 32w..32w+31 ----
  f4 c3[4][2];
#pragma unroll
  for (int mt = 0; mt < 4; ++mt)
#pragma unroll
    for (int n = 0; n < 2; ++n) c3[mt][n] = f4{0.f, 0.f, 0.f, 0.f};
  bf8 bf3[2][2];
#pragma unroll
  for (int ntl = 0; ntl < 2; ++ntl)
#pragma unroll
    for (int kt = 0; kt < 2; ++kt)
      bf3[ntl][kt] = *(const bf8*)(w3f + ((size_t)(kt * 8 + (2 * w + ntl)) * 64 + l) * 8);
#pragma unroll
  for (int mt = 0; mt < 4; ++mt)
#pragma unroll
    for (int kt = 0; kt < 2; ++kt) {
      bf8 afrag = *(const bf8*)(x2b + (mt * 16 + lc) * 72 + kt * 32 + g * 8);
#pragma unroll
      for (int ntl = 0; ntl < 2; ++ntl)
        c3[mt][ntl] = __builtin_amdgcn_mfma_f32_16x16x32_bf16(afrag, bf3[ntl][kt], c3[mt][ntl], 0, 0, 0);
    }

  // ---- inorm3 + lrelu + mean over n, in-register; write xbar bf16 to global ----
#pragma unroll
  for (int ntl = 0; ntl < 2; ++ntl) {
    float s = 0.f, q = 0.f;
#pragma unroll
    for (int mt = 0; mt < 4; ++mt)
#pragma unroll
      for (int r = 0; r < 4; ++r) { float v = c3[mt][ntl][r]; s += v; q = fmaf(v, v, q); }
    s += __shfl_xor(s, 16, 64); s += __shfl_xor(s, 32, 64);
    q += __shfl_xor(q, 16, 64); q += __shfl_xor(q, 32, 64);
    const int ch = w * 32 + ntl * 16 + lc;
    float mu  = s * (1.f / NPT);
    float inv = rsqrtf(q * (1.f / NPT) - mu * mu + EPS);
    float a = inv * pg3[ch];
    float bb = fmaf(-mu, a, pbe3[ch]);
    float m = 0.f;
#pragma unroll
    for (int mt = 0; mt < 4; ++mt)
#pragma unroll
      for (int r = 0; r < 4; ++r) m += lrelu(fmaf(c3[mt][ntl][r], a, bb));
    m += __shfl_xor(m, 16, 64); m += __shfl_xor(m, 32, 64);
    if (g == 0) xbar_out[(size_t)p * 128 + ch] = f2bf(m * (1.f / NPT));
  }
}

// ==================== kernel 2: MFMA tail, G=8 b's per block ====================
// A layout in LDS: [b_loc][9][SP] bf16, row 8 = zeros (2-tap overflow).
// bias7 applies to output rows with n==7 (folded-conv1 edge); pass bias7==bias otherwise.
template<int KT, int NT, int TS, int SPI, int SPO, bool ACT>
__device__ __forceinline__ void mfma_conv(const unsigned short* __restrict__ xin,
    unsigned short* __restrict__ xout, const unsigned short* __restrict__ wfr,
    const float* __restrict__ bias, const float* __restrict__ bias7, int w, int l) {
  const int g = l >> 4, lc = l & 15;
  const int arow = w * 16 + lc, abl = arow >> 3, an = arow & 7;
  f4 acc[NT];
#pragma unroll
  for (int nt = 0; nt < NT; ++nt) acc[nt] = f4{0.f, 0.f, 0.f, 0.f};
#pragma unroll
  for (int kt = 0; kt < KT; ++kt) {
    const int k0 = kt * 32 + g * 8;
    const int tap = k0 / TS, c = k0 - tap * TS;
    bf8 a = *(const bf8*)(xin + (abl * 9 + an + tap) * SPI + c);
#pragma unroll
    for (int nt = 0; nt < NT; ++nt) {
      bf8 b = *(const bf8*)(wfr + ((size_t)(kt * NT + nt) * 64 + l) * 8);
      acc[nt] = __builtin_amdgcn_mfma_f32_16x16x32_bf16(a, b, acc[nt], 0, 0, 0);
    }
  }
  const int orow0 = w * 16 + g * 4;
#pragma unroll
  for (int nt = 0; nt < NT; ++nt) {
    const float bv  = bias[nt * 16 + lc];
    const float bv7 = bias7[nt * 16 + lc];
#pragma unroll
    for (int r = 0; r < 4; ++r) {
      const int rr = orow0 + r, obl = rr >> 3, on = rr & 7;
      float v = acc[nt][r] + (on == 7 ? bv7 : bv);
      if (ACT) v = lrelu(v);
      xout[(obl * 9 + on) * SPO + nt * 16 + lc] = f2bf(v);
    }
  }
}

// dense 512->128 over [8 b][8 n][64 ch] (K-split over 4 waves, partials to LDS)
__device__ __forceinline__ void mfma_dense512(const unsigned short* __restrict__ xin,
    float* __restrict__ P, const unsigned short* __restrict__ wfr, int w, int l) {
  const int g = l >> 4, lc = l & 15;
  const int bl = lc & 7;                 // rows 8-15 duplicate rows 0-7
  f4 acc[8];
#pragma unroll
  for (int nt = 0; nt < 8; ++nt) acc[nt] = f4{0.f, 0.f, 0.f, 0.f};
#pragma unroll
  for (int kt2 = 0; kt2 < 4; ++kt2) {
    const int kt = w * 4 + kt2;
    const int k0 = kt * 32 + g * 8;
    const int n = k0 >> 6, c = k0 & 63;
    bf8 a = *(const bf8*)(xin + (bl * 9 + n) * 72 + c);
#pragma unroll
    for (int nt = 0; nt < 8; ++nt) {
      bf8 b = *(const bf8*)(wfr + ((size_t)(kt * 8 + nt) * 64 + l) * 8);
      acc[nt] = __builtin_amdgcn_mfma_f32_16x16x32_bf16(a, b, acc[nt], 0, 0, 0);
    }
  }
  if (g < 2) {
#pragma unroll
    for (int nt = 0; nt < 8; ++nt)
#pragma unroll
      for (int r = 0; r < 4; ++r) {
        const int rr = g * 4 + r;       // 0..7
        P[(w * 8 + rr) * 128 + nt * 16 + lc] = acc[nt][r];
      }
  }
}

__global__ __launch_bounds__(THREADS)
void tail_mfma_kernel(const unsigned short* __restrict__ xbar, const float* __restrict__ state,
    const unsigned short* __restrict__ wf,
    const float* __restrict__ mb1p, const float* __restrict__ mb1p7,
    const float* __restrict__ mb2, const float* __restrict__ mb3,
    const float* __restrict__ mb4, const float* __restrict__ mdb,
    const float* __restrict__ sb1, const float* __restrict__ sb2, const float* __restrict__ sb3,
    const float* __restrict__ sb4, const float* __restrict__ sdb,
    float* __restrict__ femb, float* __restrict__ semb)
{
  const int t = threadIdx.x, l = t & 63, w = t >> 6;
  const bool merge = blockIdx.x < 128;
  const int bg = merge ? blockIdx.x : blockIdx.x - 128;

  __shared__ unsigned short lds[24768];           // 49.5 KB
  unsigned short* BufX = lds;                     // [8][9][136] xin / L3-out [8][9][72] / partials
  unsigned short* BufY = lds + 9792;              // L1-out [8][9][136] / L4-out [8][9][72]
  unsigned short* BufZ = lds + 19584;             // L2-out [8][9][72]

  // zero: BufX fully; BufY row-8 (stride 136); BufZ row-8 (stride 72)
  { unsigned* z = (unsigned*)BufX; for (int i = t; i < 4896; i += THREADS) z[i] = 0; }
  for (int i = t; i < 8 * 136; i += THREADS) BufY[((i / 136) * 9 + 8) * 136 + (i % 136)] = 0;
  for (int i = t; i < 8 * 72;  i += THREADS) BufZ[((i / 72)  * 9 + 8) * 72  + (i % 72)]  = 0;

  if (merge) {
    for (int i = t; i < 1024; i += THREADS) {     // 8b x 8n x 16 chunks of 8 bf16
      int bl = i >> 7, rem = i & 127, n = rem >> 4, sl = rem & 15;
      bf8 v = *(const bf8*)(xbar + (size_t)((bg * 8 + bl) * 8 + n) * 128 + sl * 8);
      *(bf8*)(BufX + (bl * 9 + n) * 136 + sl * 8) = v;
    }
  } else {
    for (int i = t; i < 2304; i += THREADS) {     // 8b x 8n x 36
      int bl = i / 288, rem = i % 288, n = rem / 36, c = rem % 36;
      BufX[(bl * 9 + n) * 48 + c] = f2bf(state[((size_t)(bg * 8 + bl) * 8 + n) * 36 + c]);
    }
  }
  __syncthreads();

  if (merge) mfma_conv<8, 8, 128, 136, 136, true>(BufX, BufY, wf + WOFF_MW1, mb1p, mb1p7, w, l);
  else       mfma_conv<3, 8,  48,  48, 136, true>(BufX, BufY, wf + WOFF_SW1, sb1, sb1, w, l);
  __syncthreads();
  if (merge) mfma_conv<8, 4, 128, 136, 72, true>(BufY, BufZ, wf + WOFF_MW2, mb2, mb2, w, l);
  else       mfma_conv<8, 4, 128, 136, 72, true>(BufY, BufZ, wf + WOFF_SW2, sb2, sb2, w, l);
  // BufX is dead; set up L3's zero row-8 (stride 72)
  __syncthreads();
  for (int i = t; i < 8 * 72; i += THREADS) BufX[((i / 72) * 9 + 8) * 72 + (i % 72)] = 0;
  __syncthreads();
  if (merge) mfma_conv<4, 4, 64, 72, 72, true>(BufZ, BufX, wf + WOFF_MW3, mb3, mb3, w, l);
  else       mfma_conv<4, 4, 64, 72, 72, true>(BufZ, BufX, wf + WOFF_SW3, sb3, sb3, w, l);
  __syncthreads();
  if (merge) mfma_conv<4, 4, 64, 72, 72, true >(BufX, BufY, wf + WOFF_MW4, mb4, mb4, w, l);
  else       mfma_conv<4, 4, 64, 72, 72, false>(BufX, BufY, wf + WOFF_SW4, sb4, sb4, w, l);
  __syncthreads();

  float* P = (float*)lds;                         // 16 KB partials (BufX region, dead)
  mfma_dense512(BufY, P, wf + (merge ? WOFF_MDW : WOFF_SDW), w, l);
  __syncthreads();

  const float* bias = merge ? mdb : sdb;
  float* outg = (merge ? femb : semb) + (size_t)bg * 1024;
  for (int i = t; i < 1024; i += THREADS) {
    int ch = i & 127, b = i >> 7;
    outg[i] = bias[ch] + P[(0 * 8 + b) * 128 + ch] + P[(1 * 8 + b) * 128 + ch]
                       + P[(2 * 8 + b) * 128 + ch] + P[(3 * 8 + b) * 128 + ch];
  }
}

// ==================== kernel 3: control head, one wave per b ====================
template<int CIN, int COUT, bool ACT>
__device__ __forceinline__ void wave_dense(const float* __restrict__ in, float* __restrict__ out,
                                           const float* __restrict__ W, const float* __restrict__ bias, int l) {
  if constexpr (COUT >= 64) {
    constexpr int NC = COUT / 64;
    const int d0 = l * NC;
    float acc[NC];
#pragma unroll
    for (int k = 0; k < NC; ++k) acc[k] = bias[d0 + k];
#pragma unroll 4
    for (int c4 = 0; c4 < CIN / 4; ++c4) {
      v4f x4 = *(const v4f*)(in + 4 * c4);
#pragma unroll
      for (int j = 0; j < 4; ++j) {
        const float* wr = W + (4 * c4 + j) * COUT + d0;
#pragma unroll
        for (int k = 0; k < NC; ++k) acc[k] = fmaf(x4[j], wr[k], acc[k]);
      }
    }
#pragma unroll
    for (int k = 0; k < NC; ++k) out[d0 + k] = ACT ? lrelu(acc[k]) : acc[k];
  } else {
    if (l < COUT) {
      float acc = bias[l];
#pragma unroll 4
      for (int c4 = 0; c4 < CIN / 4; ++c4) {
        v4f x4 = *(const v4f*)(in + 4 * c4);
#pragma unroll
        for (int j = 0; j < 4; ++j) acc = fmaf(x4[j], W[(4 * c4 + j) * COUT + l], acc);
      }
      out[l] = ACT ? lrelu(acc) : acc;
    }
  }
}

__global__ __launch_bounds__(THREADS)
void head_kernel(const float* __restrict__ femb, const float* __restrict__ semb,
    const float* __restrict__ cw1, const float* __restrict__ cb1,
    const float* __restrict__ cw2, const float* __restrict__ cb2,
    const float* __restrict__ cw3, const float* __restrict__ cb3,
    const float* __restrict__ cw4, const float* __restrict__ cb4,
    float* __restrict__ out)
{
  const int t = threadIdx.x, l = t & 63, w = t >> 6;
  const int b = blockIdx.x * 4 + w;
  __shared__ float cat[4][256];
  __shared__ float hb[4][232];    // h1 128 | h2 64 | h3 32 (+pad)

  cat[w][l]       = femb[(size_t)b * 128 + l];
  cat[w][64 + l]  = femb[(size_t)b * 128 + 64 + l];
  cat[w][128 + l] = semb[(size_t)b * 128 + l];
  cat[w][192 + l] = semb[(size_t)b * 128 + 64 + l];
  __syncthreads();
  wave_dense<256, 128, true>(cat[w], hb[w], cw1, cb1, l);
  __syncthreads();
  wave_dense<128, 64, true>(hb[w], hb[w] + 128, cw2, cb2, l);
  __syncthreads();
  wave_dense<64, 32, true>(hb[w] + 128, hb[w] + 192, cw3, cb3, l);
  __syncthreads();
  if (l < 4) {
    float acc = cb4[l];
#pragma unroll
    for (int c = 0; c < 32; ++c) acc = fmaf(hb[w][192 + c], cw4[c * 4 + l], acc);
    out[(size_t)b * 4 + l] = (l == 0) ? 21.f / (1.f + expf(-acc)) : 6.f * tanhf(acc);
  }
}

extern "C" void kernel_launch(void* const* d_in, const int* in_sizes, int n_in,
                              void* d_out, int out_size, void* d_ws, size_t ws_size,
                              hipStream_t stream) {
  const float* p[44];
  for (int i = 0; i < 44; ++i) p[i] = (const float*)d_in[i];

  unsigned short* xbar_bf = (unsigned short*)d_ws;                     // 2 MB
  float* femb  = (float*)((char*)d_ws + 2097152);                      // 512 KB
  float* semb  = (float*)((char*)d_ws + 2621440);                      // 512 KB
  unsigned short* wf = (unsigned short*)((char*)d_ws + 3145728);       // 505856 B
  float* mb1p  = (float*)((char*)d_ws + 3651584);                      // 512 B
  float* mb1p7 = (float*)((char*)d_ws + 3652096);                      // 512 B

  prep_weights<<<125, THREADS, 0, stream>>>(
      p[2], p[6], p[10],
      p[14], p[15], p[16], p[17],
      p[18], p[20], p[22], p[24],
      p[26], p[28], p[30], p[32], p[34],
      wf, mb1p, mb1p7);

  pointnet_kernel<<<1024 * S, THREADS, 0, stream>>>(
      p[0],
      wf + WOFF_PNW1, p[4], p[5],
      wf + WOFF_PNW2, p[8], p[9],
      wf + WOFF_PNW3, p[12], p[13],
      xbar_bf);

  tail_mfma_kernel<<<256, THREADS, 0, stream>>>(
      xbar_bf, p[1], wf,
      mb1p, mb1p7, p[19], p[21], p[23], p[25],
      p[27], p[29], p[31], p[33], p[35],
      femb, semb);

  head_kernel<<<256, THREADS, 0, stream>>>(
      femb, semb,
      p[36], p[37], p[38], p[39], p[40], p[41], p[42], p[43],
      (float*)d_out);
}